// Round 11
// baseline (407.200 us; speedup 1.0000x reference)
//
#include <hip/hip_runtime.h>

#define NB 4096
#define MM 128
#define NN 96
#define LL 20
#define UTS 72   // Ut row stride in u16 (144B): b128-aligned, 2-way banks (free)

typedef __attribute__((ext_vector_type(8))) short bf16x8;
typedef __attribute__((ext_vector_type(4))) float f32x4;
typedef __attribute__((ext_vector_type(4))) unsigned int u32x4;

__device__ __forceinline__ unsigned short rne16(float f) {
    unsigned u = __float_as_uint(f);
    return (unsigned short)((u + 0x7fffu + ((u >> 16) & 1u)) >> 16);
}
__device__ __forceinline__ unsigned pack2(float a, float b) {
    return (unsigned)rne16(a) | ((unsigned)rne16(b) << 16);
}
__device__ __forceinline__ float bperm_f(int srcB, float v) {
    return __int_as_float(__builtin_amdgcn_ds_bpermute(srcB, __float_as_int(v)));
}

// One wave = one batch (R9 structure, zero inter-wave coupling).
// Phase A runs as 3 sequential J-pass sweeps (restaging Ut each pass) so the
// accumulator peak is acc[6][2] (48 AGPR) instead of acc[6][7] (168):
//   pass 0: J-tiles {0,1} + y (accY broadcast)   -> afr[0..1], hty4
//   pass 1: J-tiles {2,3}                        -> afr[2..3]
//   pass 2: J-tiles {4,5}                        -> afr[4..5]
// Transition per pass = R9-verified symmetry + quad-bpermute formula.
__global__ __launch_bounds__(64) __attribute__((amdgpu_waves_per_eu(3)))
void pg_kernel(const float* __restrict__ x_ini,
               const float* __restrict__ y,
               const float* __restrict__ H,
               const float* __restrict__ xt,
               const float* __restrict__ grad_ss,
               const float* __restrict__ extra_ss,
               const float* __restrict__ gamma1,
               float* __restrict__ out)
{
    __shared__ __align__(16) unsigned short Ut[97 * UTS]; // H^T bf16, row c = H col c; row 96 = y
    __shared__ __align__(16) unsigned yxL[48];            // packed bf16 yx
    __shared__ float par[3][LL];

    const int b    = blockIdx.x;
    const int lane = threadIdx.x;
    const int m15  = lane & 15;
    const int g4   = lane >> 4;

    if (lane < LL) {
        par[0][lane] = grad_ss[lane];
        par[1][lane] = extra_ss[lane];
        par[2][lane] = gamma1[lane];
    }

    const float* Hb = H + (size_t)b * (MM * NN);
    const int srcL[2] = { (m15 + 16 * (2 * (g4 & 1) + 0)) << 2,
                          (m15 + 16 * (2 * (g4 & 1) + 1)) << 2 };
    const bool hiHalf = (g4 >> 1) != 0;

    bf16x8 afr[6][3];      // phase-B A-frags, built incrementally
    float  hty4[4] = {0, 0, 0, 0};

    #pragma unroll
    for (int pass = 0; pass < 3; ++pass) {
        const int J0 = 2 * pass;
        f32x4 acc[6][2];
        f32x4 accY[6];
        #pragma unroll
        for (int I = 0; I < 6; ++I) {
            #pragma unroll
            for (int r = 0; r < 4; ++r) {
                acc[I][0][r] = 0.f; acc[I][1][r] = 0.f;
                if (pass == 0) accY[I][r] = 0.f;
            }
        }

        for (int kh = 0; kh < 2; ++kh) {
            __syncthreads();   // previous contents' frag reads complete
            // ---- stage: lane = H row (kh*64+lane), transpose-write 96 bf16 ----
            const float* rsrc = Hb + (size_t)(kh * 64 + lane) * NN;
            #pragma unroll
            for (int ch = 0; ch < 4; ++ch) {
                float4 v[6];
                #pragma unroll
                for (int i = 0; i < 6; ++i) v[i] = *(const float4*)(rsrc + ch * 24 + 4 * i);
                #pragma unroll
                for (int i = 0; i < 6; ++i) {
                    const int c = ch * 24 + 4 * i;
                    Ut[(c + 0) * UTS + lane] = rne16(v[i].x);
                    Ut[(c + 1) * UTS + lane] = rne16(v[i].y);
                    Ut[(c + 2) * UTS + lane] = rne16(v[i].z);
                    Ut[(c + 3) * UTS + lane] = rne16(v[i].w);
                }
            }
            if (pass == 0) Ut[96 * UTS + lane] = rne16(y[(size_t)b * MM + kh * 64 + lane]);
            __syncthreads();

            #pragma unroll
            for (int s = 0; s < 2; ++s) {          // two K=32 steps per half
                const int ko = s * 32 + g4 * 8;
                bf16x8 fB0 = *(const bf16x8*)&Ut[((J0 + 0) * 16 + m15) * UTS + ko];
                bf16x8 fB1 = *(const bf16x8*)&Ut[((J0 + 1) * 16 + m15) * UTS + ko];
                bf16x8 fY;
                if (pass == 0) fY = *(const bf16x8*)&Ut[96 * UTS + ko];  // broadcast row
                #pragma unroll
                for (int I = 0; I < 6; ++I) {
                    bf16x8 fa = *(const bf16x8*)&Ut[(I * 16 + m15) * UTS + ko];
                    acc[I][0] = __builtin_amdgcn_mfma_f32_16x16x32_bf16(fa, fB0, acc[I][0], 0, 0, 0);
                    acc[I][1] = __builtin_amdgcn_mfma_f32_16x16x32_bf16(fa, fB1, acc[I][1], 0, 0, 0);
                    if (pass == 0)
                        accY[I] = __builtin_amdgcn_mfma_f32_16x16x32_bf16(fa, fY, accY[I], 0, 0, 0);
                }
            }
        }

        // ---- transition for this pass's 2 col-tiles (R9-verified formula) ----
        #pragma unroll
        for (int jl = 0; jl < 2; ++jl) {
            unsigned pkA[6], pkB[6];
            #pragma unroll
            for (int kt = 0; kt < 6; ++kt) {
                pkA[kt] = pack2(acc[kt][jl][0], acc[kt][jl][1]);
                pkB[kt] = pack2(acc[kt][jl][2], acc[kt][jl][3]);
            }
            #pragma unroll
            for (int kk = 0; kk < 3; ++kk) {
                u32x4 w;
                #pragma unroll
                for (int p = 0; p < 4; ++p) {
                    unsigned sa = (p & 1) ? pkB[2 * kk]     : pkA[2 * kk];
                    unsigned sb = (p & 1) ? pkB[2 * kk + 1] : pkA[2 * kk + 1];
                    int va = __builtin_amdgcn_ds_bpermute(srcL[p >> 1], (int)sa);
                    int vb = __builtin_amdgcn_ds_bpermute(srcL[p >> 1], (int)sb);
                    w[p] = (unsigned)(hiHalf ? vb : va);
                }
                afr[J0 + jl][kk] = __builtin_bit_cast(bf16x8, w);
            }
        }

        // ---- hty extraction (pass 0 only; R9-verified pattern) ----
        if (pass == 0) {
            const int srcC = (16 * g4) << 2;
            #pragma unroll
            for (int r = 0; r < 4; ++r) {
                float v0 = bperm_f(srcC, accY[0][r]);
                float v1 = bperm_f(srcC, accY[1][r]);
                float v2 = bperm_f(srcC, accY[2][r]);
                float v3 = bperm_f(srcC, accY[3][r]);
                float v4 = bperm_f(srcC, accY[4][r]);
                float v5 = bperm_f(srcC, accY[5][r]);
                float s = v0;
                s = (m15 == 1) ? v1 : s;
                s = (m15 == 2) ? v2 : s;
                s = (m15 == 3) ? v3 : s;
                s = (m15 == 4) ? v4 : s;
                s = (m15 == 5) ? v5 : s;
                hty4[r] = s;
            }
        }
    }

    // ================= Phase B: 20 iterations, wave-local (R9 verbatim) =================
    const bool wr = (m15 < 6);
    const int  rb = m15 * 16 + g4 * 4;         // writer owns rows rb..rb+3
    float yx4[4] = {0, 0, 0, 0}, xc4[4] = {0, 0, 0, 0};
    if (wr) {
        float4 xi = *(const float4*)(x_ini + (size_t)b * NN + rb);
        yx4[0] = xi.x; yx4[1] = xi.y; yx4[2] = xi.z; yx4[3] = xi.w;
        xc4[0] = xi.x; xc4[1] = xi.y; xc4[2] = xi.z; xc4[3] = xi.w;
        yxL[(rb >> 1) + 0] = pack2(yx4[0], yx4[1]);
        yxL[(rb >> 1) + 1] = pack2(yx4[2], yx4[3]);
    }
    __syncthreads();

    for (int t = 0; t < LL; ++t) {
        bf16x8 bf[3];                          // broadcast yx k-slices
        #pragma unroll
        for (int kk = 0; kk < 3; ++kk)
            bf[kk] = *(const bf16x8*)&yxL[kk * 16 + g4 * 4];
        f32x4 aD[6];
        #pragma unroll
        for (int Ip = 0; Ip < 6; ++Ip)
            #pragma unroll
            for (int r = 0; r < 4; ++r) aD[Ip][r] = 0.f;
        #pragma unroll
        for (int kk = 0; kk < 3; ++kk)
            #pragma unroll
            for (int Ip = 0; Ip < 6; ++Ip)
                aD[Ip] = __builtin_amdgcn_mfma_f32_16x16x32_bf16(afr[Ip][kk], bf[kk], aD[Ip], 0, 0, 0);
        f32x4 am = aD[0];
        am = (m15 == 1) ? aD[1] : am;
        am = (m15 == 2) ? aD[2] : am;
        am = (m15 == 3) ? aD[3] : am;
        am = (m15 == 4) ? aD[4] : am;
        am = (m15 == 5) ? aD[5] : am;

        if (wr) {
            const float gs = par[0][t], es = par[1][t], gmv = par[2][t];
            #pragma unroll
            for (int r = 0; r < 4; ++r) {
                float xb  = fmaf(-2.0f * gs, am[r] - hty4[r], yx4[r]);
                float cen = 2.0f * fminf(fmaxf(rintf(xb * 0.5f), -1.0f), 1.0f);
                float z   = gmv * (xb - cen);
                float e   = __expf(-z);
                float ply = fmaf(2.0f, __builtin_amdgcn_rcpf(1.0f + e), -1.0f);
                float yxn = fmaf(es, ply - xc4[r], ply);
                xc4[r] = ply;
                yx4[r] = yxn;
            }
            if (t + 1 < LL) {
                yxL[(rb >> 1) + 0] = pack2(yx4[0], yx4[1]);
                yxL[(rb >> 1) + 1] = pack2(yx4[2], yx4[3]);
            }
        }
        __syncthreads();   // 1-wave block: lgkmcnt ordering for yxL
    }

    // ================= epilogue =================
    float part = 0.f;
    if (wr) {
        float4 xo;
        xo.x = xc4[0]; xo.y = xc4[1]; xo.z = xc4[2]; xo.w = xc4[3];
        *(float4*)(out + (size_t)b * NN + rb) = xo;
        float4 xr = *(const float4*)(xt + (size_t)b * NN + rb);
        float d0 = xc4[0] - xr.x, d1 = xc4[1] - xr.y;
        float d2 = xc4[2] - xr.z, d3 = xc4[3] - xr.w;
        part = (d0 * d0 + d1 * d1) + (d2 * d2 + d3 * d3);
    }
    #pragma unroll
    for (int m = 1; m < 64; m <<= 1) part += __shfl_xor(part, m, 64);
    if (lane == 0) atomicAdd(out + (size_t)NB * NN, part);
}

extern "C" void kernel_launch(void* const* d_in, const int* in_sizes, int n_in,
                              void* d_out, int out_size, void* d_ws, size_t ws_size,
                              hipStream_t stream) {
    const float* x_ini    = (const float*)d_in[0];
    const float* y        = (const float*)d_in[1];
    const float* H        = (const float*)d_in[2];
    const float* xt       = (const float*)d_in[3];
    const float* grad_ss  = (const float*)d_in[4];
    const float* extra_ss = (const float*)d_in[5];
    const float* gamma1   = (const float*)d_in[6];
    float* out = (float*)d_out;

    hipMemsetAsync(out + (size_t)NB * NN, 0, sizeof(float), stream);
    pg_kernel<<<NB, 64, 0, stream>>>(x_ini, y, H, xt, grad_ss, extra_ss, gamma1, out);
}

// Round 12
// 100.683 us; speedup vs baseline: 4.0444x; 4.0444x over previous
//
#include <hip/hip_runtime.h>

#define NB 4096
#define MM 128
#define NN 96
#define LL 20
#define UTS 72   // Ut row stride in u16 (144B): b128-aligned, 2-way banks (free)

typedef __attribute__((ext_vector_type(8))) short bf16x8;
typedef __attribute__((ext_vector_type(4))) float f32x4;
typedef __attribute__((ext_vector_type(4))) unsigned int u32x4;

__device__ __forceinline__ unsigned short rne16(float f) {
    unsigned u = __float_as_uint(f);
    return (unsigned short)((u + 0x7fffu + ((u >> 16) & 1u)) >> 16);
}
__device__ __forceinline__ unsigned pack2(float a, float b) {
    return (unsigned)rne16(a) | ((unsigned)rne16(b) << 16);
}
__device__ __forceinline__ float bperm_f(int srcB, float v) {
    return __int_as_float(__builtin_amdgcn_ds_bpermute(srcB, __float_as_int(v)));
}

// Block = 128 threads (2 waves) = 1 batch.
// Phase A (J-split, 6 one-time barriers): wave w owns HTH col-tiles J=3w..3w+2
//   (acc[6][3] = 72 AGPR) + accY (both waves, redundant -> no hty exchange).
// Transition (R9/R11-validated bpermute formula) -> 9 frags/wave -> one-time
//   LDS exchange (aliases dead Ut) -> each wave holds ALL 18 afr frags.
// Phase B: fully redundant per wave, wave-private yxL, ZERO barriers
//   (R8-fista validated pattern). Wave 0 writes the outputs.
__global__ __launch_bounds__(128) __attribute__((amdgpu_waves_per_eu(2)))
void pg_kernel(const float* __restrict__ x_ini,
               const float* __restrict__ y,
               const float* __restrict__ H,
               const float* __restrict__ xt,
               const float* __restrict__ grad_ss,
               const float* __restrict__ extra_ss,
               const float* __restrict__ gamma1,
               float* __restrict__ out)
{
    __shared__ __align__(16) unsigned U[18 * 64 * 4];  // 18.4KB: Ut u16[97*72] (13.9KB) then afrX[18][64][4]
    __shared__ __align__(16) unsigned yxL[2][48];      // wave-private packed yx
    __shared__ float par[3][LL];

    const int b    = blockIdx.x;
    const int tid  = threadIdx.x;
    const int lane = tid & 63;
    const int wid  = tid >> 6;
    const int m15  = lane & 15;
    const int g4   = lane >> 4;

    unsigned short* Ut = (unsigned short*)U;

    if (tid < LL) {
        par[0][tid] = grad_ss[tid];
        par[1][tid] = extra_ss[tid];
        par[2][tid] = gamma1[tid];
    }

    // ================= Phase A: this wave's J-tiles of HTH + HTy =================
    f32x4 acc[6][3];   // [ktile][jl], global J = wid*3 + jl
    f32x4 accY[6];
    #pragma unroll
    for (int kt = 0; kt < 6; ++kt) {
        #pragma unroll
        for (int jl = 0; jl < 3; ++jl)
            #pragma unroll
            for (int r = 0; r < 4; ++r) acc[kt][jl][r] = 0.f;
        #pragma unroll
        for (int r = 0; r < 4; ++r) accY[kt][r] = 0.f;
    }

    const float* Hb  = H + (size_t)b * (MM * NN);
    const int    r64 = tid >> 1;   // H row within k-half
    const int    qh  = tid & 1;    // 48-col half

    for (int kh = 0; kh < 2; ++kh) {
        if (kh) __syncthreads();   // half-0 frag reads complete before restage
        {
            const float* rsrc = Hb + (size_t)(kh * 64 + r64) * NN + qh * 48;
            #pragma unroll
            for (int c4 = 0; c4 < 3; ++c4) {   // chunks of 4 float4 (small reg window)
                float4 v[4];
                #pragma unroll
                for (int i = 0; i < 4; ++i) v[i] = *(const float4*)(rsrc + c4 * 16 + 4 * i);
                #pragma unroll
                for (int i = 0; i < 4; ++i) {
                    const int c = qh * 48 + c4 * 16 + 4 * i;
                    Ut[(c + 0) * UTS + r64] = rne16(v[i].x);
                    Ut[(c + 1) * UTS + r64] = rne16(v[i].y);
                    Ut[(c + 2) * UTS + r64] = rne16(v[i].z);
                    Ut[(c + 3) * UTS + r64] = rne16(v[i].w);
                }
            }
            if (tid < 64) Ut[96 * UTS + tid] = rne16(y[(size_t)b * MM + kh * 64 + tid]);
        }
        __syncthreads();

        #pragma unroll
        for (int s = 0; s < 2; ++s) {          // two K=32 steps per half
            const int ko = s * 32 + g4 * 8;
            bf16x8 fB[3];
            #pragma unroll
            for (int jl = 0; jl < 3; ++jl)
                fB[jl] = *(const bf16x8*)&Ut[((wid * 3 + jl) * 16 + m15) * UTS + ko];
            bf16x8 fY = *(const bf16x8*)&Ut[96 * UTS + ko];   // broadcast row 96 = y
            #pragma unroll
            for (int I = 0; I < 6; ++I) {
                bf16x8 fa = *(const bf16x8*)&Ut[(I * 16 + m15) * UTS + ko];
                #pragma unroll
                for (int jl = 0; jl < 3; ++jl)
                    acc[I][jl] = __builtin_amdgcn_mfma_f32_16x16x32_bf16(fa, fB[jl], acc[I][jl], 0, 0, 0);
                accY[I] = __builtin_amdgcn_mfma_f32_16x16x32_bf16(fa, fY, accY[I], 0, 0, 0);
            }
        }
    }
    __syncthreads();   // ALL waves' Ut reads done -> U reusable as afrX

    // ====== Transition (R9-validated formula) + one-time frag exchange ======
    const int srcL[2] = { (m15 + 16 * (2 * (g4 & 1) + 0)) << 2,
                          (m15 + 16 * (2 * (g4 & 1) + 1)) << 2 };
    const bool hiHalf = (g4 >> 1) != 0;
    #pragma unroll
    for (int jl = 0; jl < 3; ++jl) {
        unsigned pkA[6], pkB[6];
        #pragma unroll
        for (int kt = 0; kt < 6; ++kt) {
            pkA[kt] = pack2(acc[kt][jl][0], acc[kt][jl][1]);
            pkB[kt] = pack2(acc[kt][jl][2], acc[kt][jl][3]);
        }
        #pragma unroll
        for (int kk = 0; kk < 3; ++kk) {
            u32x4 w;
            #pragma unroll
            for (int p = 0; p < 4; ++p) {
                unsigned sa = (p & 1) ? pkB[2 * kk]     : pkA[2 * kk];
                unsigned sb = (p & 1) ? pkB[2 * kk + 1] : pkA[2 * kk + 1];
                int va = __builtin_amdgcn_ds_bpermute(srcL[p >> 1], (int)sa);
                int vb = __builtin_amdgcn_ds_bpermute(srcL[p >> 1], (int)sb);
                w[p] = (unsigned)(hiHalf ? vb : va);
            }
            const int f = (wid * 3 + jl) * 3 + kk;
            *(u32x4*)&U[(f * 64 + lane) * 4] = w;
        }
    }
    // hty extraction (own wave, R9-validated pattern)
    float hty4[4];
    {
        const int srcC = (16 * g4) << 2;
        #pragma unroll
        for (int r = 0; r < 4; ++r) {
            float v0 = bperm_f(srcC, accY[0][r]);
            float v1 = bperm_f(srcC, accY[1][r]);
            float v2 = bperm_f(srcC, accY[2][r]);
            float v3 = bperm_f(srcC, accY[3][r]);
            float v4 = bperm_f(srcC, accY[4][r]);
            float v5 = bperm_f(srcC, accY[5][r]);
            float s = v0;
            s = (m15 == 1) ? v1 : s;
            s = (m15 == 2) ? v2 : s;
            s = (m15 == 3) ? v3 : s;
            s = (m15 == 4) ? v4 : s;
            s = (m15 == 5) ? v5 : s;
            hty4[r] = s;
        }
    }
    __syncthreads();   // afrX visible to both waves

    bf16x8 afr[6][3];
    #pragma unroll
    for (int Ip = 0; Ip < 6; ++Ip)
        #pragma unroll
        for (int kk = 0; kk < 3; ++kk)
            afr[Ip][kk] = __builtin_bit_cast(bf16x8, *(const u32x4*)&U[((Ip * 3 + kk) * 64 + lane) * 4]);

    // ================= Phase B: 20 iterations, wave-private, NO barriers =================
    const bool wr = (m15 < 6);
    const int  rb = m15 * 16 + g4 * 4;
    float yx4[4] = {0, 0, 0, 0}, xc4[4] = {0, 0, 0, 0};
    if (wr) {
        float4 xi = *(const float4*)(x_ini + (size_t)b * NN + rb);
        yx4[0] = xi.x; yx4[1] = xi.y; yx4[2] = xi.z; yx4[3] = xi.w;
        xc4[0] = xi.x; xc4[1] = xi.y; xc4[2] = xi.z; xc4[3] = xi.w;
        yxL[wid][(rb >> 1) + 0] = pack2(yx4[0], yx4[1]);
        yxL[wid][(rb >> 1) + 1] = pack2(yx4[2], yx4[3]);
    }
    __builtin_amdgcn_sched_barrier(0);

    for (int t = 0; t < LL; ++t) {
        bf16x8 bf[3];
        #pragma unroll
        for (int kk = 0; kk < 3; ++kk)
            bf[kk] = *(const bf16x8*)&yxL[wid][kk * 16 + g4 * 4];
        f32x4 aD[6];
        #pragma unroll
        for (int Ip = 0; Ip < 6; ++Ip)
            #pragma unroll
            for (int r = 0; r < 4; ++r) aD[Ip][r] = 0.f;
        #pragma unroll
        for (int kk = 0; kk < 3; ++kk)
            #pragma unroll
            for (int Ip = 0; Ip < 6; ++Ip)
                aD[Ip] = __builtin_amdgcn_mfma_f32_16x16x32_bf16(afr[Ip][kk], bf[kk], aD[Ip], 0, 0, 0);
        f32x4 am = aD[0];
        am = (m15 == 1) ? aD[1] : am;
        am = (m15 == 2) ? aD[2] : am;
        am = (m15 == 3) ? aD[3] : am;
        am = (m15 == 4) ? aD[4] : am;
        am = (m15 == 5) ? aD[5] : am;

        if (wr) {
            const float gs = par[0][t], es = par[1][t], gmv = par[2][t];
            #pragma unroll
            for (int r = 0; r < 4; ++r) {
                float xb  = fmaf(-2.0f * gs, am[r] - hty4[r], yx4[r]);
                float cen = 2.0f * fminf(fmaxf(rintf(xb * 0.5f), -1.0f), 1.0f);
                float z   = gmv * (xb - cen);
                float e   = __expf(-z);
                float ply = fmaf(2.0f, __builtin_amdgcn_rcpf(1.0f + e), -1.0f);
                float yxn = fmaf(es, ply - xc4[r], ply);
                xc4[r] = ply;
                yx4[r] = yxn;
            }
            if (t + 1 < LL) {
                yxL[wid][(rb >> 1) + 0] = pack2(yx4[0], yx4[1]);
                yxL[wid][(rb >> 1) + 1] = pack2(yx4[2], yx4[3]);
            }
        }
        __builtin_amdgcn_sched_barrier(0);
    }

    // ================= epilogue: wave 0 only =================
    if (wid == 0) {
        float part = 0.f;
        if (wr) {
            float4 xo;
            xo.x = xc4[0]; xo.y = xc4[1]; xo.z = xc4[2]; xo.w = xc4[3];
            *(float4*)(out + (size_t)b * NN + rb) = xo;
            float4 xr = *(const float4*)(xt + (size_t)b * NN + rb);
            float d0 = xc4[0] - xr.x, d1 = xc4[1] - xr.y;
            float d2 = xc4[2] - xr.z, d3 = xc4[3] - xr.w;
            part = (d0 * d0 + d1 * d1) + (d2 * d2 + d3 * d3);
        }
        #pragma unroll
        for (int m = 1; m < 64; m <<= 1) part += __shfl_xor(part, m, 64);
        if (lane == 0) atomicAdd(out + (size_t)NB * NN, part);
    }
}

extern "C" void kernel_launch(void* const* d_in, const int* in_sizes, int n_in,
                              void* d_out, int out_size, void* d_ws, size_t ws_size,
                              hipStream_t stream) {
    const float* x_ini    = (const float*)d_in[0];
    const float* y        = (const float*)d_in[1];
    const float* H        = (const float*)d_in[2];
    const float* xt       = (const float*)d_in[3];
    const float* grad_ss  = (const float*)d_in[4];
    const float* extra_ss = (const float*)d_in[5];
    const float* gamma1   = (const float*)d_in[6];
    float* out = (float*)d_out;

    hipMemsetAsync(out + (size_t)NB * NN, 0, sizeof(float), stream);
    pg_kernel<<<NB, 128, 0, stream>>>(x_ini, y, H, xt, grad_ss, extra_ss, gamma1, out);
}